// Round 1
// baseline (367.620 us; speedup 1.0000x reference)
//
#include <hip/hip_runtime.h>
#include <hip/hip_fp16.h>

// Problem constants: B=4, N=2048, D=1024, H=16, DH=64
// M = B*N = 8192 tokens.

typedef _Float16 half8 __attribute__((ext_vector_type(8)));
typedef float f32x4 __attribute__((ext_vector_type(4)));

#define DEV __device__ __forceinline__
#define MFMA16(a, b, c) __builtin_amdgcn_mfma_f32_16x16x32_f16(a, b, c, 0, 0, 0)

DEV void gload_lds16(const void* g, void* l) {
  __builtin_amdgcn_global_load_lds(
      (const __attribute__((address_space(1))) void*)g,
      (__attribute__((address_space(3))) void*)l, 16, 0, 0);
}

// ---------------- cast f32 -> f16 (8 elems / thread) ----------------
__global__ __launch_bounds__(256) void cast_f32h(const float* __restrict__ s,
                                                 __half* __restrict__ d, int n8) {
  int i = blockIdx.x * 256 + threadIdx.x;
  if (i >= n8) return;
  const float4* sp = (const float4*)s + (size_t)i * 2;
  float4 a = sp[0], b = sp[1];
  half8 h;
  h[0] = (_Float16)a.x; h[1] = (_Float16)a.y; h[2] = (_Float16)a.z; h[3] = (_Float16)a.w;
  h[4] = (_Float16)b.x; h[5] = (_Float16)b.y; h[6] = (_Float16)b.z; h[7] = (_Float16)b.w;
  *((half8*)d + i) = h;
}

// ---------------- 128x128 GEMM, NT (both operands K-contiguous), K=1024 ----
// A: [M][1024] f16 row-major.  Bm: [Ncols][1024] f16 row-major (= W, since
// y = x @ W^T).  MODE 0: QKV epilogue -> oh = qkv buffer, per-head layout,
// q scaled by 8 (sqrt(DH), faithful to ref bug), biases b0/b1/b2.
// MODE 1: proj epilogue -> of = f32 out, bias b0.
template <int MODE>
__global__ __launch_bounds__(256) void gemm128(
    const __half* __restrict__ A, const __half* __restrict__ Bm,
    const float* __restrict__ b0, const float* __restrict__ b1,
    const float* __restrict__ b2, __half* __restrict__ oh,
    float* __restrict__ of) {
  const int m0 = blockIdx.y * 128;
  const int n0 = blockIdx.x * 128;
  const int tid = threadIdx.x;
  const int w = tid >> 6, lane = tid & 63;
  const int lr = lane & 15, lq = lane >> 4;
  const int wr = w >> 1, wc = w & 1;

  __shared__ alignas(16) __half As[128 * 64];
  __shared__ alignas(16) __half Bs[128 * 64];

  f32x4 acc[4][4] = {};

  const int arow = lane >> 3;        // 0..7 row within 8-row chunk
  const int acol = (lane & 7) * 8;   // halves
  const __half* Agp = A + ((size_t)m0 + w * 32 + arow) * 1024 + acol;
  const __half* Bgp = Bm + ((size_t)n0 + w * 32 + arow) * 1024 + acol;

  for (int kt = 0; kt < 16; ++kt) {
#pragma unroll
    for (int j = 0; j < 4; ++j) {
      gload_lds16(Agp + j * 8192 + kt * 64, As + (w * 4 + j) * 512);
      gload_lds16(Bgp + j * 8192 + kt * 64, Bs + (w * 4 + j) * 512);
    }
    __syncthreads();
#pragma unroll
    for (int s = 0; s < 2; ++s) {
      half8 af[4], bf[4];
#pragma unroll
      for (int i = 0; i < 4; ++i) {
        af[i] = *(const half8*)(As + (wr * 64 + i * 16 + lr) * 64 + s * 32 + lq * 8);
        bf[i] = *(const half8*)(Bs + (wc * 64 + i * 16 + lr) * 64 + s * 32 + lq * 8);
      }
#pragma unroll
      for (int mi = 0; mi < 4; ++mi)
#pragma unroll
        for (int ni = 0; ni < 4; ++ni)
          acc[mi][ni] = MFMA16(af[mi], bf[ni], acc[mi][ni]);
    }
    __syncthreads();
  }

  if (MODE == 0) {
    // col = e' in [0,3072): t = e'>>10 (0=q,1=k,2=v), e = e'&1023, h=e>>6, dh=e&63
    // write fp16 to qkv[t][(b*16+h)][n][dh]
#pragma unroll
    for (int ni = 0; ni < 4; ++ni) {
      int col = n0 + wc * 64 + ni * 16 + lr;
      int t = col >> 10, e = col & 1023;
      const float* bb = (t == 0) ? b0 : ((t == 1) ? b1 : b2);
      float bias = bb[e];
      float scale = (t == 0) ? 8.0f : 1.0f;
      int hh = e >> 6, dh = e & 63;
      __half* base = oh + (size_t)t * 8388608 + dh;
#pragma unroll
      for (int mi = 0; mi < 4; ++mi)
#pragma unroll
        for (int r = 0; r < 4; ++r) {
          int row = m0 + wr * 64 + mi * 16 + lq * 4 + r;
          int b_ = row >> 11, n = row & 2047;
          float v = (acc[mi][ni][r] + bias) * scale;
          base[(((size_t)(b_ * 16 + hh) * 2048 + n) * 64)] = __float2half(v);
        }
    }
  } else {
#pragma unroll
    for (int ni = 0; ni < 4; ++ni) {
      int col = n0 + wc * 64 + ni * 16 + lr;
      float bias = b0[col];
#pragma unroll
      for (int mi = 0; mi < 4; ++mi)
#pragma unroll
        for (int r = 0; r < 4; ++r) {
          int row = m0 + wr * 64 + mi * 16 + lq * 4 + r;
          of[(size_t)row * 1024 + col] = acc[mi][ni][r] + bias;
        }
    }
  }
}

// ---------------- V transpose: [bh][2048][64] -> [bh][64][2048] ------------
__global__ __launch_bounds__(256) void vtrans(const __half* __restrict__ V,
                                              __half* __restrict__ Vt) {
  const int bh = blockIdx.y;
  const int n0 = blockIdx.x * 64;
  const int tid = threadIdx.x;
  __shared__ alignas(16) __half t[64][80];  // pad: 160B row stride, 16B aligned

  const __half* src = V + ((size_t)bh * 2048 + n0) * 64;
#pragma unroll
  for (int j = 0; j < 2; ++j) {
    int lin = (tid + j * 256) * 8;
    int r = lin >> 6, c = lin & 63;  // r = n row, c = dh col
    *(half8*)&t[r][c] = *(const half8*)(src + (size_t)r * 64 + c);
  }
  __syncthreads();
  __half* dst = Vt + (size_t)bh * 64 * 2048 + n0;
#pragma unroll
  for (int j = 0; j < 2; ++j) {
    int lin = (tid + j * 256) * 8;
    int dh = lin >> 6, c = lin & 63;  // c = n offset
    half8 v;
#pragma unroll
    for (int i = 0; i < 8; ++i) v[i] = *(_Float16*)&t[c + i][dh];
    *(half8*)(dst + (size_t)dh * 2048 + c) = v;
  }
}

// ---------------- causal flash attention ----------------------------------
// Q,K: [bh][2048][64] f16 (Q pre-scaled by 8).  Vt: [bh][64][2048] f16.
// O: [b][n][h*64+dh] f16 (= [8192][1024], ready for proj GEMM).
// Block: 256 thr = 4 waves; 64 queries/block (16 rows/wave); KVBLK = 64.
__global__ __launch_bounds__(256) void attn64(const __half* __restrict__ Q,
                                              const __half* __restrict__ K,
                                              const __half* __restrict__ Vt,
                                              __half* __restrict__ O) {
  const int bh = blockIdx.y;
  const int q0 = blockIdx.x * 64;
  const int b = bh >> 4, h = bh & 15;
  const int tid = threadIdx.x;
  const int wq = tid >> 6;
  const int lane = tid & 63;
  const int lr = lane & 15, lq = lane >> 4;

  __shared__ alignas(16) __half Ks[64 * 64];
  __shared__ alignas(16) __half Vs[64 * 64];
  __shared__ alignas(16) __half Ps[4][16 * 64];

  // Q fragments (A-operand): row = lane&15, k = lq*8 + s*32
  const __half* Qp = Q + ((size_t)bh * 2048 + q0 + wq * 16) * 64;
  half8 qf0 = *(const half8*)(Qp + lr * 64 + lq * 8);
  half8 qf1 = *(const half8*)(Qp + lr * 64 + 32 + lq * 8);

  f32x4 oacc[4] = {};
  float m_r[4] = {-INFINITY, -INFINITY, -INFINITY, -INFINITY};
  float l_r[4] = {0.f, 0.f, 0.f, 0.f};

  const __half* Kb = K + (size_t)bh * 2048 * 64;
  const __half* Vb = Vt + (size_t)bh * 64 * 2048;
  const int nkt = (q0 >> 6) + 1;

  for (int kt = 0; kt < nkt; ++kt) {
    const int k0 = kt * 64;
    // --- stage K tile [64 k][64 dh] and V tile [64 dh][64 k], XOR-swizzled
#pragma unroll
    for (int j = 0; j < 2; ++j) {
      int lin = (tid + j * 256) * 8;
      int r = lin >> 6, c = lin & 63;
      half8 kv = *(const half8*)(Kb + (size_t)(k0 + r) * 64 + c);
      *(half8*)((char*)Ks + ((r * 128 + c * 2) ^ ((r & 7) << 4))) = kv;
      half8 vv = *(const half8*)(Vb + (size_t)r * 2048 + k0 + c);
      *(half8*)((char*)Vs + ((r * 128 + c * 2) ^ ((r & 7) << 4))) = vv;
    }
    __syncthreads();

    // --- S = Q K^T  (16 q rows x 64 keys per wave)
    f32x4 sacc[4] = {};
#pragma unroll
    for (int nt = 0; nt < 4; ++nt) {
      int row = nt * 16 + lr;  // key index in tile
      half8 kb0 = *(const half8*)((char*)Ks + ((row * 128 + lq * 16) ^ ((row & 7) << 4)));
      half8 kb1 = *(const half8*)((char*)Ks + ((row * 128 + 64 + lq * 16) ^ ((row & 7) << 4)));
      sacc[nt] = MFMA16(qf0, kb0, sacc[nt]);
      sacc[nt] = MFMA16(qf1, kb1, sacc[nt]);
    }

    // --- causal mask (only diagonal tile: k0 == q0)
    if (kt == nkt - 1) {
#pragma unroll
      for (int nt = 0; nt < 4; ++nt)
#pragma unroll
        for (int rr = 0; rr < 4; ++rr) {
          int colk = k0 + nt * 16 + lr;
          int rowq = q0 + wq * 16 + lq * 4 + rr;
          if (colk > rowq) sacc[nt][rr] = -INFINITY;
        }
    }

    // --- online softmax (rows = lq*4 + rr; cols spread over 16 lanes x 4 nt)
    float mt[4];
#pragma unroll
    for (int rr = 0; rr < 4; ++rr) {
      mt[rr] = fmaxf(fmaxf(sacc[0][rr], sacc[1][rr]), fmaxf(sacc[2][rr], sacc[3][rr]));
    }
#pragma unroll
    for (int off = 1; off < 16; off <<= 1)
#pragma unroll
      for (int rr = 0; rr < 4; ++rr) mt[rr] = fmaxf(mt[rr], __shfl_xor(mt[rr], off));

    float alpha[4];
#pragma unroll
    for (int rr = 0; rr < 4; ++rr) {
      float mn = fmaxf(m_r[rr], mt[rr]);
      alpha[rr] = __expf(m_r[rr] - mn);
      m_r[rr] = mn;
    }
    float rs[4] = {0.f, 0.f, 0.f, 0.f};
#pragma unroll
    for (int nt = 0; nt < 4; ++nt)
#pragma unroll
      for (int rr = 0; rr < 4; ++rr) {
        float p = __expf(sacc[nt][rr] - m_r[rr]);
        rs[rr] += p;
        int prow = lq * 4 + rr, pcol = nt * 16 + lr;
        *(__half*)((char*)Ps[wq] + ((prow * 128 + pcol * 2) ^ ((prow & 7) << 4))) =
            __float2half(p);
      }
#pragma unroll
    for (int off = 1; off < 16; off <<= 1)
#pragma unroll
      for (int rr = 0; rr < 4; ++rr) rs[rr] += __shfl_xor(rs[rr], off);
#pragma unroll
    for (int rr = 0; rr < 4; ++rr) l_r[rr] = l_r[rr] * alpha[rr] + rs[rr];
#pragma unroll
    for (int dt = 0; dt < 4; ++dt)
#pragma unroll
      for (int rr = 0; rr < 4; ++rr) oacc[dt][rr] *= alpha[rr];

    __syncthreads();  // P visible (also orders LDS writes vs reads)

    // --- PV: A = P (row=lr, k contiguous), B = V^T tile
    half8 pa0 = *(const half8*)((char*)Ps[wq] + ((lr * 128 + lq * 16) ^ ((lr & 7) << 4)));
    half8 pa1 = *(const half8*)((char*)Ps[wq] + ((lr * 128 + 64 + lq * 16) ^ ((lr & 7) << 4)));
#pragma unroll
    for (int dt = 0; dt < 4; ++dt) {
      int row = dt * 16 + lr;  // dh
      half8 vb0 = *(const half8*)((char*)Vs + ((row * 128 + lq * 16) ^ ((row & 7) << 4)));
      half8 vb1 = *(const half8*)((char*)Vs + ((row * 128 + 64 + lq * 16) ^ ((row & 7) << 4)));
      oacc[dt] = MFMA16(pa0, vb0, oacc[dt]);
      oacc[dt] = MFMA16(pa1, vb1, oacc[dt]);
    }
    __syncthreads();  // done with Ks/Vs/Ps before next stage
  }

  float inv[4];
#pragma unroll
  for (int rr = 0; rr < 4; ++rr) inv[rr] = 1.0f / l_r[rr];
  __half* Op = O + ((size_t)b * 2048 + q0 + wq * 16) * 1024 + h * 64;
#pragma unroll
  for (int dt = 0; dt < 4; ++dt)
#pragma unroll
    for (int rr = 0; rr < 4; ++rr)
      Op[(size_t)(lq * 4 + rr) * 1024 + dt * 16 + lr] =
          __float2half(oacc[dt][rr] * inv[rr]);
}

// ---------------- launch ---------------------------------------------------
extern "C" void kernel_launch(void* const* d_in, const int* in_sizes, int n_in,
                              void* d_out, int out_size, void* d_ws,
                              size_t ws_size, hipStream_t stream) {
  const float* x = (const float*)d_in[0];
  const float* Wq = (const float*)d_in[1];
  const float* bq = (const float*)d_in[2];
  const float* Wk = (const float*)d_in[3];
  const float* bk = (const float*)d_in[4];
  const float* Wv = (const float*)d_in[5];
  const float* bv = (const float*)d_in[6];
  const float* Wp = (const float*)d_in[7];
  const float* bp = (const float*)d_in[8];

  // workspace layout (bytes)
  char* ws = (char*)d_ws;
  const size_t XB = 0;                       // 8192*1024*2 = 16777216
  const size_t WQKV = XB + 16777216;         // 3072*1024*2 = 6291456
  const size_t WPB = WQKV + 6291456;         // 1024*1024*2 = 2097152
  const size_t QKV = WPB + 2097152;          // 3 * 8388608 halves = 50331648
  const size_t VT = QKV + 50331648;          // 16777216
  const size_t OB = VT + 16777216;           // 16777216  (total ~88 MiB)

  __half* xb = (__half*)(ws + XB);
  __half* wqkv = (__half*)(ws + WQKV);
  __half* wpb = (__half*)(ws + WPB);
  __half* qkv = (__half*)(ws + QKV);
  __half* vt = (__half*)(ws + VT);
  __half* ob = (__half*)(ws + OB);

  cast_f32h<<<4096, 256, 0, stream>>>(x, xb, 1048576);
  cast_f32h<<<512, 256, 0, stream>>>(Wq, wqkv, 131072);
  cast_f32h<<<512, 256, 0, stream>>>(Wk, wqkv + 1048576, 131072);
  cast_f32h<<<512, 256, 0, stream>>>(Wv, wqkv + 2097152, 131072);
  cast_f32h<<<512, 256, 0, stream>>>(Wp, wpb, 131072);

  // QKV: M=8192, N=3072
  gemm128<0><<<dim3(24, 64), 256, 0, stream>>>(xb, wqkv, bq, bk, bv, qkv, nullptr);
  // V -> V^T per head
  vtrans<<<dim3(32, 64), 256, 0, stream>>>(qkv + 2 * 8388608, vt);
  // attention
  attn64<<<dim3(32, 64), 256, 0, stream>>>(qkv, qkv + 8388608, vt, ob);
  // proj: M=8192, N=1024, f32 out + bias
  gemm128<1><<<dim3(8, 64), 256, 0, stream>>>(ob, wpb, bp, nullptr, nullptr,
                                              nullptr, (float*)d_out);
}

// Round 2
// 229.552 us; speedup vs baseline: 1.6015x; 1.6015x over previous
//
#include <hip/hip_runtime.h>
#include <hip/hip_fp16.h>

// Problem constants: B=4, N=2048, D=1024, H=16, DH=64
// M = B*N = 8192 tokens.

typedef _Float16 half8 __attribute__((ext_vector_type(8)));
typedef float f32x4 __attribute__((ext_vector_type(4)));

#define DEV __device__ __forceinline__
#define MFMA16(a, b, c) __builtin_amdgcn_mfma_f32_16x16x32_f16(a, b, c, 0, 0, 0)

DEV void gload_lds16(const void* g, void* l) {
  __builtin_amdgcn_global_load_lds(
      (const __attribute__((address_space(1))) void*)g,
      (__attribute__((address_space(3))) void*)l, 16, 0, 0);
}

// ---------------- cast f32 -> f16 (8 elems / thread) ----------------
__global__ __launch_bounds__(256) void cast_f32h(const float* __restrict__ s,
                                                 __half* __restrict__ d, int n8) {
  int i = blockIdx.x * 256 + threadIdx.x;
  if (i >= n8) return;
  const float4* sp = (const float4*)s + (size_t)i * 2;
  float4 a = sp[0], b = sp[1];
  half8 h;
  h[0] = (_Float16)a.x; h[1] = (_Float16)a.y; h[2] = (_Float16)a.z; h[3] = (_Float16)a.w;
  h[4] = (_Float16)b.x; h[5] = (_Float16)b.y; h[6] = (_Float16)b.z; h[7] = (_Float16)b.w;
  *((half8*)d + i) = h;
}

// ---------------- 128x128 GEMM, NT (both operands K-contiguous), K=1024 ----
template <int MODE>
__global__ __launch_bounds__(256) void gemm128(
    const __half* __restrict__ A, const __half* __restrict__ Bm,
    const float* __restrict__ b0, const float* __restrict__ b1,
    const float* __restrict__ b2, __half* __restrict__ oh,
    float* __restrict__ of) {
  const int m0 = blockIdx.y * 128;
  const int n0 = blockIdx.x * 128;
  const int tid = threadIdx.x;
  const int w = tid >> 6, lane = tid & 63;
  const int lr = lane & 15, lq = lane >> 4;
  const int wr = w >> 1, wc = w & 1;

  __shared__ alignas(16) __half As[128 * 64];
  __shared__ alignas(16) __half Bs[128 * 64];

  f32x4 acc[4][4] = {};

  const int arow = lane >> 3;        // 0..7 row within 8-row chunk
  const int acol = (lane & 7) * 8;   // halves
  const __half* Agp = A + ((size_t)m0 + w * 32 + arow) * 1024 + acol;
  const __half* Bgp = Bm + ((size_t)n0 + w * 32 + arow) * 1024 + acol;

  for (int kt = 0; kt < 16; ++kt) {
#pragma unroll
    for (int j = 0; j < 4; ++j) {
      gload_lds16(Agp + j * 8192 + kt * 64, As + (w * 4 + j) * 512);
      gload_lds16(Bgp + j * 8192 + kt * 64, Bs + (w * 4 + j) * 512);
    }
    __syncthreads();
#pragma unroll
    for (int s = 0; s < 2; ++s) {
      half8 af[4], bf[4];
#pragma unroll
      for (int i = 0; i < 4; ++i) {
        af[i] = *(const half8*)(As + (wr * 64 + i * 16 + lr) * 64 + s * 32 + lq * 8);
        bf[i] = *(const half8*)(Bs + (wc * 64 + i * 16 + lr) * 64 + s * 32 + lq * 8);
      }
#pragma unroll
      for (int mi = 0; mi < 4; ++mi)
#pragma unroll
        for (int ni = 0; ni < 4; ++ni)
          acc[mi][ni] = MFMA16(af[mi], bf[ni], acc[mi][ni]);
    }
    __syncthreads();
  }

  if (MODE == 0) {
#pragma unroll
    for (int ni = 0; ni < 4; ++ni) {
      int col = n0 + wc * 64 + ni * 16 + lr;
      int t = col >> 10, e = col & 1023;
      const float* bb = (t == 0) ? b0 : ((t == 1) ? b1 : b2);
      float bias = bb[e];
      float scale = (t == 0) ? 8.0f : 1.0f;
      int hh = e >> 6, dh = e & 63;
      __half* base = oh + (size_t)t * 8388608 + dh;
#pragma unroll
      for (int mi = 0; mi < 4; ++mi)
#pragma unroll
        for (int r = 0; r < 4; ++r) {
          int row = m0 + wr * 64 + mi * 16 + lq * 4 + r;
          int b_ = row >> 11, n = row & 2047;
          float v = (acc[mi][ni][r] + bias) * scale;
          base[(((size_t)(b_ * 16 + hh) * 2048 + n) * 64)] = __float2half(v);
        }
    }
  } else {
#pragma unroll
    for (int ni = 0; ni < 4; ++ni) {
      int col = n0 + wc * 64 + ni * 16 + lr;
      float bias = b0[col];
#pragma unroll
      for (int mi = 0; mi < 4; ++mi)
#pragma unroll
        for (int r = 0; r < 4; ++r) {
          int row = m0 + wr * 64 + mi * 16 + lq * 4 + r;
          of[(size_t)row * 1024 + col] = acc[mi][ni][r] + bias;
        }
    }
  }
}

// ---------------- V transpose: [bh][2048][64] -> [bh][64][2048] ------------
__global__ __launch_bounds__(256) void vtrans(const __half* __restrict__ V,
                                              __half* __restrict__ Vt) {
  const int bh = blockIdx.y;
  const int n0 = blockIdx.x * 64;
  const int tid = threadIdx.x;
  __shared__ alignas(16) __half t[64][80];

  const __half* src = V + ((size_t)bh * 2048 + n0) * 64;
#pragma unroll
  for (int j = 0; j < 2; ++j) {
    int lin = (tid + j * 256) * 8;
    int r = lin >> 6, c = lin & 63;
    *(half8*)&t[r][c] = *(const half8*)(src + (size_t)r * 64 + c);
  }
  __syncthreads();
  __half* dst = Vt + (size_t)bh * 64 * 2048 + n0;
#pragma unroll
  for (int j = 0; j < 2; ++j) {
    int lin = (tid + j * 256) * 8;
    int dh = lin >> 6, c = lin & 63;
    half8 v;
#pragma unroll
    for (int i = 0; i < 8; ++i) v[i] = *(_Float16*)&t[c + i][dh];
    *(half8*)(dst + (size_t)dh * 2048 + c) = v;
  }
}

// ---------------- causal flash attention, 128-q blocks, 8 waves ------------
// Q,K: [bh][2048][64] f16 (Q pre-scaled by 8).  Vt: [bh][64][2048] f16.
// O: [b][n][h*64+dh] f16 (= [8192][1024], ready for proj GEMM).
// Grid: (8 pairs, 64 bh). Block = 512 thr = 8 waves; 16 q-rows/wave.
// Causal balance: block p handles q-tiles p and 15-p (34 KV tiles total).
// K/V staged via double-buffered global_load_lds with PRE-SWIZZLED global
// source (LDS dest linear); counted vmcnt(2), raw barriers (T3/T4).
__global__ __launch_bounds__(512, 4) void attn128(const __half* __restrict__ Q,
                                                  const __half* __restrict__ K,
                                                  const __half* __restrict__ Vt,
                                                  __half* __restrict__ O) {
  const int bh = blockIdx.y;
  const int pair = blockIdx.x;
  const int b = bh >> 4, h = bh & 15;
  const int tid = threadIdx.x;
  const int w = tid >> 6, lane = tid & 63;
  const int lr = lane & 15, lq = lane >> 4;

  __shared__ alignas(16) __half Ks[2][64 * 64];
  __shared__ alignas(16) __half Vs[2][64 * 64];
  __shared__ alignas(16) __half Ps[8][16 * 64];

  const __half* Kb = K + (size_t)bh * 2048 * 64;
  const __half* Vb = Vt + (size_t)bh * 64 * 2048;

  // staging: LDS slot o = w*1024 + lane*16 bytes; inverse of the read swizzle
  // byte = (r*128 + c*2) ^ ((r&7)<<4)  collapses to:
  const int srow = lane >> 3;                    // row within 8-row chunk
  const int scol = ((lane & 7) ^ srow) * 8;      // pre-swizzled col (halves)

  for (int half_ = 0; half_ < 2; ++half_) {
    const int qt = half_ ? (15 - pair) : pair;
    const int q0 = qt * 128;
    const int ktend = 2 * qt + 2;
    const int rmin = q0 + w * 16;  // wave's first q row

    // Q fragments (A-operand)
    const __half* Qp = Q + ((size_t)bh * 2048 + q0 + w * 16) * 64;
    half8 qf0 = *(const half8*)(Qp + lr * 64 + lq * 8);
    half8 qf1 = *(const half8*)(Qp + lr * 64 + 32 + lq * 8);

    f32x4 oacc[4] = {};
    float m_r[4] = {-INFINITY, -INFINITY, -INFINITY, -INFINITY};
    float l_r[4] = {0.f, 0.f, 0.f, 0.f};

    // prologue: stage tile 0 -> buf 0
    gload_lds16(Kb + (size_t)(0 + w * 8 + srow) * 64 + scol, Ks[0] + w * 512);
    gload_lds16(Vb + (size_t)(w * 8 + srow) * 2048 + 0 + scol, Vs[0] + w * 512);
    asm volatile("" ::: "memory");

    for (int kt = 0; kt < ktend; ++kt) {
      const int cur = kt & 1;
      const int k0 = kt * 64;
      if (kt + 1 < ktend) {
        const int kn = k0 + 64;
        gload_lds16(Kb + (size_t)(kn + w * 8 + srow) * 64 + scol,
                    Ks[cur ^ 1] + w * 512);
        gload_lds16(Vb + (size_t)(w * 8 + srow) * 2048 + kn + scol,
                    Vs[cur ^ 1] + w * 512);
        asm volatile("s_waitcnt vmcnt(2)" ::: "memory");
      } else {
        asm volatile("s_waitcnt vmcnt(0)" ::: "memory");
      }
      __builtin_amdgcn_s_barrier();
      asm volatile("" ::: "memory");

      const char* Kc = (const char*)Ks[cur];
      const char* Vc = (const char*)Vs[cur];
      const bool active = (k0 <= rmin + 15);  // else tile fully masked for wave
      if (active) {
        // --- S = Q K^T  (16 q rows x 64 keys per wave)
        f32x4 sacc[4] = {};
#pragma unroll
        for (int nt = 0; nt < 4; ++nt) {
          int row = nt * 16 + lr;  // key index in tile
          half8 kb0 = *(const half8*)(Kc + ((row * 128 + lq * 16) ^ ((row & 7) << 4)));
          half8 kb1 = *(const half8*)(Kc + ((row * 128 + 64 + lq * 16) ^ ((row & 7) << 4)));
          sacc[nt] = MFMA16(qf0, kb0, sacc[nt]);
          sacc[nt] = MFMA16(qf1, kb1, sacc[nt]);
        }

        // --- causal mask (diagonal sub-tiles only)
        if (k0 + 63 > rmin) {
#pragma unroll
          for (int nt = 0; nt < 4; ++nt)
#pragma unroll
            for (int rr = 0; rr < 4; ++rr) {
              int colk = k0 + nt * 16 + lr;
              int rowq = rmin + lq * 4 + rr;
              if (colk > rowq) sacc[nt][rr] = -INFINITY;
            }
        }

        // --- online softmax
        float mt[4];
#pragma unroll
        for (int rr = 0; rr < 4; ++rr)
          mt[rr] = fmaxf(fmaxf(sacc[0][rr], sacc[1][rr]),
                         fmaxf(sacc[2][rr], sacc[3][rr]));
#pragma unroll
        for (int off = 1; off < 16; off <<= 1)
#pragma unroll
          for (int rr = 0; rr < 4; ++rr) mt[rr] = fmaxf(mt[rr], __shfl_xor(mt[rr], off));

        float alpha[4];
#pragma unroll
        for (int rr = 0; rr < 4; ++rr) {
          float mn = fmaxf(m_r[rr], mt[rr]);
          alpha[rr] = __expf(m_r[rr] - mn);
          m_r[rr] = mn;
        }
        float rs[4] = {0.f, 0.f, 0.f, 0.f};
#pragma unroll
        for (int nt = 0; nt < 4; ++nt)
#pragma unroll
          for (int rr = 0; rr < 4; ++rr) {
            float p = __expf(sacc[nt][rr] - m_r[rr]);
            rs[rr] += p;
            int prow = lq * 4 + rr, pcol = nt * 16 + lr;
            *(__half*)((char*)Ps[w] + ((prow * 128 + pcol * 2) ^ ((prow & 7) << 4))) =
                __float2half(p);
          }
#pragma unroll
        for (int off = 1; off < 16; off <<= 1)
#pragma unroll
          for (int rr = 0; rr < 4; ++rr) rs[rr] += __shfl_xor(rs[rr], off);
#pragma unroll
        for (int rr = 0; rr < 4; ++rr) l_r[rr] = l_r[rr] * alpha[rr] + rs[rr];
#pragma unroll
        for (int dt = 0; dt < 4; ++dt)
#pragma unroll
          for (int rr = 0; rr < 4; ++rr) oacc[dt][rr] *= alpha[rr];

        // --- PV: A = P row (k contiguous), B = V^T tile.  P is per-wave
        // private LDS; within-wave write->read ordering is compiler-tracked.
        half8 pa0 = *(const half8*)((char*)Ps[w] + ((lr * 128 + lq * 16) ^ ((lr & 7) << 4)));
        half8 pa1 = *(const half8*)((char*)Ps[w] + ((lr * 128 + 64 + lq * 16) ^ ((lr & 7) << 4)));
#pragma unroll
        for (int dt = 0; dt < 4; ++dt) {
          int row = dt * 16 + lr;  // dh
          half8 vb0 = *(const half8*)(Vc + ((row * 128 + lq * 16) ^ ((row & 7) << 4)));
          half8 vb1 = *(const half8*)(Vc + ((row * 128 + 64 + lq * 16) ^ ((row & 7) << 4)));
          oacc[dt] = MFMA16(pa0, vb0, oacc[dt]);
          oacc[dt] = MFMA16(pa1, vb1, oacc[dt]);
        }
      }
      // all LDS reads of buf[cur] must COMPLETE before other waves' next
      // stage overwrites it
      asm volatile("s_waitcnt lgkmcnt(0)" ::: "memory");
      __builtin_amdgcn_s_barrier();
      asm volatile("" ::: "memory");
    }

    // epilogue: O write for this q-tile
    float inv[4];
#pragma unroll
    for (int rr = 0; rr < 4; ++rr) inv[rr] = 1.0f / l_r[rr];
    __half* Op = O + ((size_t)b * 2048 + q0 + w * 16) * 1024 + h * 64;
#pragma unroll
    for (int dt = 0; dt < 4; ++dt)
#pragma unroll
      for (int rr = 0; rr < 4; ++rr)
        Op[(size_t)(lq * 4 + rr) * 1024 + dt * 16 + lr] =
            __float2half(oacc[dt][rr] * inv[rr]);
  }
}

// ---------------- launch ---------------------------------------------------
extern "C" void kernel_launch(void* const* d_in, const int* in_sizes, int n_in,
                              void* d_out, int out_size, void* d_ws,
                              size_t ws_size, hipStream_t stream) {
  const float* x = (const float*)d_in[0];
  const float* Wq = (const float*)d_in[1];
  const float* bq = (const float*)d_in[2];
  const float* Wk = (const float*)d_in[3];
  const float* bk = (const float*)d_in[4];
  const float* Wv = (const float*)d_in[5];
  const float* bv = (const float*)d_in[6];
  const float* Wp = (const float*)d_in[7];
  const float* bp = (const float*)d_in[8];

  // workspace layout (bytes)
  char* ws = (char*)d_ws;
  const size_t XB = 0;                       // 8192*1024*2 = 16777216
  const size_t WQKV = XB + 16777216;         // 3072*1024*2 = 6291456
  const size_t WPB = WQKV + 6291456;         // 1024*1024*2 = 2097152
  const size_t QKV = WPB + 2097152;          // 3 * 8388608 halves = 50331648
  const size_t VT = QKV + 50331648;          // 16777216
  const size_t OB = VT + 16777216;           // 16777216  (total ~88 MiB)

  __half* xb = (__half*)(ws + XB);
  __half* wqkv = (__half*)(ws + WQKV);
  __half* wpb = (__half*)(ws + WPB);
  __half* qkv = (__half*)(ws + QKV);
  __half* vt = (__half*)(ws + VT);
  __half* ob = (__half*)(ws + OB);

  cast_f32h<<<4096, 256, 0, stream>>>(x, xb, 1048576);
  cast_f32h<<<512, 256, 0, stream>>>(Wq, wqkv, 131072);
  cast_f32h<<<512, 256, 0, stream>>>(Wk, wqkv + 1048576, 131072);
  cast_f32h<<<512, 256, 0, stream>>>(Wv, wqkv + 2097152, 131072);
  cast_f32h<<<512, 256, 0, stream>>>(Wp, wpb, 131072);

  // QKV: M=8192, N=3072
  gemm128<0><<<dim3(24, 64), 256, 0, stream>>>(xb, wqkv, bq, bk, bv, qkv, nullptr);
  // V -> V^T per head
  vtrans<<<dim3(32, 64), 256, 0, stream>>>(qkv + 2 * 8388608, vt);
  // attention (causal-balanced pairs)
  attn128<<<dim3(8, 64), 512, 0, stream>>>(qkv, qkv + 8388608, vt, ob);
  // proj: M=8192, N=1024, f32 out + bias
  gemm128<1><<<dim3(8, 64), 256, 0, stream>>>(ob, wpb, bp, nullptr, nullptr,
                                              nullptr, (float*)d_out);
}